// Round 14
// baseline (711.926 us; speedup 1.0000x reference)
//
#include <hip/hip_runtime.h>
#include <hip/hip_fp16.h>
#include <hip/hip_cooperative_groups.h>

namespace cg = cooperative_groups;

#define NEG_SLOPE 0.2f
#define EPSF 1e-16f

typedef _Float16 half8 __attribute__((ext_vector_type(8)));
typedef float floatx4 __attribute__((ext_vector_type(4)));

// ---------- MFMA fp16 GEMM + fused alpha epilogue ----------
// C[M,BN] = X[M,128] @ W[128,BN]; X fp16 or fp32 (converted in-register),
// W fp32 -> fp16 in LDS, fp32 MFMA accum. Per wave: 16 rows x BN.
// Layouts (gfx950 16x16x32): A row=lane&15, k=8*(lane>>4)+i; B col=lane&15,
// same k; C/D col=lane&15, row=4*(lane>>4)+reg  [guide-verified].
template<int BN, int HEADS, typename XT>
__global__ __launch_bounds__(256) void gemm_mfma(const XT* __restrict__ X,
                                                 const float* __restrict__ W,
                                                 const float* __restrict__ asrc,
                                                 const float* __restrict__ adst,
                                                 __half* __restrict__ OutH,
                                                 float* __restrict__ AS,
                                                 float* __restrict__ AD, int N) {
    constexpr int KP = 136;           // padded k-stride (f16) for Wt
    constexpr int NF = BN / 16;       // 8 (BN=128) or 4 (BN=64)
    __shared__ _Float16 Wt[BN][KP];
    const int tid = threadIdx.x;
    const int wave = tid >> 6, lane = tid & 63;
    const int r = lane & 15;          // A-row-in-tile / B,C col-in-frag
    const int g = lane >> 4;          // k-group / C row-group
    const int row0 = blockIdx.x * 64 + wave * 16;

    // stage Wt[n][k] = (f16) W[k][n]
    for (int idx = tid; idx < 128 * (BN / 4); idx += 256) {
        int k = idx / (BN / 4), n4 = idx % (BN / 4);
        float4 w4 = *(const float4*)&W[(size_t)k * BN + n4 * 4];
        Wt[n4 * 4 + 0][k] = (_Float16)w4.x;
        Wt[n4 * 4 + 1][k] = (_Float16)w4.y;
        Wt[n4 * 4 + 2][k] = (_Float16)w4.z;
        Wt[n4 * 4 + 3][k] = (_Float16)w4.w;
    }
    __syncthreads();

    const int arow = row0 + r;
    const int arow_c = (arow < N) ? arow : (N - 1);   // clamp; bad rows never stored

    floatx4 acc[NF];
#pragma unroll
    for (int n = 0; n < NF; ++n) acc[n] = (floatx4)(0.f);

#pragma unroll
    for (int ks = 0; ks < 4; ++ks) {   // K-steps of 32
        half8 afrag;
        if constexpr (sizeof(XT) == 2) {
            afrag = *(const half8*)&X[(size_t)arow_c * 128 + ks * 32 + g * 8];
        } else {
            const float* xp = (const float*)&X[(size_t)arow_c * 128 + ks * 32 + g * 8];
            float4 a = *(const float4*)xp;
            float4 b = *(const float4*)(xp + 4);
            afrag[0] = (_Float16)a.x; afrag[1] = (_Float16)a.y;
            afrag[2] = (_Float16)a.z; afrag[3] = (_Float16)a.w;
            afrag[4] = (_Float16)b.x; afrag[5] = (_Float16)b.y;
            afrag[6] = (_Float16)b.z; afrag[7] = (_Float16)b.w;
        }
#pragma unroll
        for (int n = 0; n < NF; ++n) {
            half8 bfrag = *(const half8*)&Wt[n * 16 + r][ks * 32 + g * 8];
            acc[n] = __builtin_amdgcn_mfma_f32_16x16x32_f16(afrag, bfrag, acc[n], 0, 0, 0);
        }
    }

    float av[NF], dv[NF];
#pragma unroll
    for (int n = 0; n < NF; ++n) { av[n] = asrc[n * 16 + r]; dv[n] = adst[n * 16 + r]; }

#pragma unroll
    for (int reg = 0; reg < 4; ++reg) {
        const int orow = row0 + g * 4 + reg;   // uniform across the 16-lane r-group
        if (orow >= N) continue;
#pragma unroll
        for (int n = 0; n < NF; ++n)
            OutH[(size_t)orow * BN + n * 16 + r] = __float2half(acc[n][reg]);
        float ps0 = 0.f, pd0 = 0.f, ps1 = 0.f, pd1 = 0.f;
#pragma unroll
        for (int n = 0; n < NF; ++n) {
            float v = acc[n][reg];
            if (HEADS == 2 && n >= NF / 2) { ps1 = fmaf(v, av[n], ps1); pd1 = fmaf(v, dv[n], pd1); }
            else                           { ps0 = fmaf(v, av[n], ps0); pd0 = fmaf(v, dv[n], pd0); }
        }
#pragma unroll
        for (int o = 1; o < 16; o <<= 1) {
            ps0 += __shfl_xor(ps0, o, 64); pd0 += __shfl_xor(pd0, o, 64);
            if (HEADS == 2) { ps1 += __shfl_xor(ps1, o, 64); pd1 += __shfl_xor(pd1, o, 64); }
        }
        if (r == 0) {
            if (HEADS == 2) {
                AS[orow * 2] = ps0; AS[orow * 2 + 1] = ps1;
                AD[orow * 2] = pd0; AD[orow * 2 + 1] = pd1;
            } else {
                AS[orow] = ps0; AD[orow] = pd0;
            }
        }
    }
}

// ---------- fused cooperative CSR build ----------
// zero(cnt) | hist(part'd) | scan_block | scan_bsum | scan_add | scatter(part'd)
// separated by grid.sync(). 1024 blocks x 256 (co-resident: 4 blocks/CU).
__global__ void csr_build_coop(const int* __restrict__ ei, int E_raw, int N,
                               int* __restrict__ cnt, int* __restrict__ offs,
                               int* __restrict__ bsum, int* __restrict__ csr_src) {
    cg::grid_group grid = cg::this_grid();
    __shared__ int wsum[4];
    const int tid = blockIdx.x * blockDim.x + threadIdx.x;
    const int nthr = gridDim.x * blockDim.x;
    const int E = E_raw + N;
    const int lane = threadIdx.x & 63, w = threadIdx.x >> 6;
    const int nb = (N + 255) / 256;

    // phase 1: zero cnt
    for (int i = tid; i < (N + 3) / 4; i += nthr)
        ((int4*)cnt)[i] = make_int4(0, 0, 0, 0);
    grid.sync();

    // phase 2: histogram, XCD-partitioned by dst range
    {
        const int part = blockIdx.x & 7;
        const int grank = blockIdx.x >> 3;
        const int gblocks = gridDim.x >> 3;
        const int t2 = grank * blockDim.x + threadIdx.x;
        const int n2 = gblocks * blockDim.x;
        const int dlo = (int)(((long long)N * part) / 8);
        const int dhi = (int)(((long long)N * (part + 1)) / 8);
        for (int e = t2; e < E; e += n2) {
            int d = (e < E_raw) ? ei[E_raw + e] : e - E_raw;
            if (d >= dlo && d < dhi) atomicAdd(&cnt[d], 1);
        }
    }
    grid.sync();

    // phase 3: per-block exclusive scan (blocks 0..nb-1)
    if (blockIdx.x < nb) {
        const int i = blockIdx.x * 256 + threadIdx.x;
        int v = (i < N) ? cnt[i] : 0;
        int incl = v;
        for (int o = 1; o < 64; o <<= 1) {
            int t = __shfl_up(incl, o, 64);
            if (lane >= o) incl += t;
        }
        if (lane == 63) wsum[w] = incl;
        __syncthreads();
        int prefix = 0;
        for (int k = 0; k < w; ++k) prefix += wsum[k];
        if (i < N) offs[i] = prefix + incl - v;
        if (threadIdx.x == 255) bsum[blockIdx.x] = prefix + incl;
        __syncthreads();
    }
    grid.sync();

    // phase 4: scan bsum (block 0; nb <= 256)
    if (blockIdx.x == 0) {
        int v = (threadIdx.x < nb) ? bsum[threadIdx.x] : 0;
        int incl = v;
        for (int o = 1; o < 64; o <<= 1) {
            int t = __shfl_up(incl, o, 64);
            if (lane >= o) incl += t;
        }
        if (lane == 63) wsum[w] = incl;
        __syncthreads();
        int prefix = 0;
        for (int k = 0; k < w; ++k) prefix += wsum[k];
        if (threadIdx.x < nb) bsum[threadIdx.x] = prefix + incl - v;
    }
    grid.sync();

    // phase 5: add block offsets
    if (blockIdx.x < nb) {
        const int i = blockIdx.x * 256 + threadIdx.x;
        if (i < N) offs[i] += bsum[blockIdx.x];
        if (i == 0) offs[N] = E;
    }
    grid.sync();

    // phase 6: scatter, XCD-partitioned; pos = offs[d] + (--cnt[d])
    {
        const int part = blockIdx.x & 7;
        const int grank = blockIdx.x >> 3;
        const int gblocks = gridDim.x >> 3;
        const int t2 = grank * blockDim.x + threadIdx.x;
        const int n2 = gblocks * blockDim.x;
        const int dlo = (int)(((long long)N * part) / 8);
        const int dhi = (int)(((long long)N * (part + 1)) / 8);
        for (int e = t2; e < E; e += n2) {
            int d = (e < E_raw) ? ei[E_raw + e] : e - E_raw;
            if (d >= dlo && d < dhi) {
                int s = (e < E_raw) ? ei[e] : d;
                int old = atomicSub(&cnt[d], 1);
                csr_src[offs[d] + old - 1] = s;
            }
        }
    }
}

// ---------- fused GAT per-dst, heads=2, fp16 H, fp16 out (R12 best) ----------
__global__ __launch_bounds__(256) void gat_csr2(const int* __restrict__ offs,
                                                const int* __restrict__ csr_src,
                                                const float* __restrict__ AS,
                                                const float* __restrict__ AD,
                                                const __half* __restrict__ H,
                                                const float* __restrict__ bias,
                                                __half* __restrict__ Out,
                                                int N, int do_relu) {
    __shared__ int   sS[4][64];
    __shared__ float sP0[4][64];
    __shared__ float sP1[4][64];
    const int lane = threadIdx.x & 63;
    const int w = threadIdx.x >> 6;
    const int wid = (int)((blockIdx.x * blockDim.x + threadIdx.x) >> 6);
    const int nw = (int)((gridDim.x * blockDim.x) >> 6);
    const int c = lane & 15;      // channels 8c..8c+7
    const int slot = lane >> 4;   // 4 edge slots
    const int myh = c >> 3;       // head owning my channels
    int* const sSw = &sS[w][0];
    const float* const myp = myh ? &sP1[w][0] : &sP0[w][0];
    const float4 bA = *(const float4*)&bias[8 * c];
    const float4 bB = *(const float4*)&bias[8 * c + 4];

    for (int n = wid; n < N; n += nw) {
        const int s0 = offs[n], s1 = offs[n + 1];
        const int deg = s1 - s0;
        const float2 adv = *(const float2*)&AD[(size_t)n * 2];
        float dn0 = 0.f, dn1 = 0.f, p0 = 0.f, p1 = 0.f;
        int sreg = 0;
        for (int i = s0 + lane; i < s1; i += 64) {
            int s = csr_src[i];
            float2 a2 = *(const float2*)&AS[(size_t)s * 2];
            float e0 = a2.x + adv.x, e1 = a2.y + adv.y;
            e0 = e0 > 0.f ? e0 : NEG_SLOPE * e0;
            e1 = e1 > 0.f ? e1 : NEG_SLOPE * e1;
            float pe0 = __expf(e0), pe1 = __expf(e1);
            dn0 += pe0; dn1 += pe1;
            if (i == s0 + lane) { sreg = s; p0 = pe0; p1 = pe1; }
        }
        for (int o = 1; o < 64; o <<= 1) {
            dn0 += __shfl_xor(dn0, o, 64);
            dn1 += __shfl_xor(dn1, o, 64);
        }
        const float myinv = 1.f / ((myh ? dn1 : dn0) + EPSF);

        float a[8];
#pragma unroll
        for (int j = 0; j < 8; ++j) a[j] = 0.f;
        if (deg <= 64) {
            sSw[lane] = sreg;       // phantom lanes: s=0, p=0
            sP0[w][lane] = p0;
            sP1[w][lane] = p1;
            const int npc = (deg + 3) >> 2;   // quads; phantom edges have p=0
            int t = 0;
            for (; t + 4 <= npc; t += 4) {
                int ss[4]; float pw[4]; uint4 hv[4];
#pragma unroll
                for (int k = 0; k < 4; ++k) {
                    int idx = 4 * (t + k) + slot;
                    ss[k] = sSw[idx];
                    pw[k] = myp[idx];
                }
#pragma unroll
                for (int k = 0; k < 4; ++k)
                    hv[k] = *(const uint4*)&H[(size_t)ss[k] * 128 + 8 * c];
#pragma unroll
                for (int k = 0; k < 4; ++k) {
                    const __half2* h2 = (const __half2*)&hv[k];
#pragma unroll
                    for (int j = 0; j < 4; ++j) {
                        float2 f = __half22float2(h2[j]);
                        a[2 * j]     = fmaf(f.x, pw[k], a[2 * j]);
                        a[2 * j + 1] = fmaf(f.y, pw[k], a[2 * j + 1]);
                    }
                }
            }
            for (; t < npc; ++t) {
                int idx = 4 * t + slot;
                int s = sSw[idx];
                float pw = myp[idx];
                uint4 hv = *(const uint4*)&H[(size_t)s * 128 + 8 * c];
                const __half2* h2 = (const __half2*)&hv;
#pragma unroll
                for (int j = 0; j < 4; ++j) {
                    float2 f = __half22float2(h2[j]);
                    a[2 * j]     = fmaf(f.x, pw, a[2 * j]);
                    a[2 * j + 1] = fmaf(f.y, pw, a[2 * j + 1]);
                }
            }
        } else {
            const float advh = myh ? adv.y : adv.x;
            for (int i = s0 + slot; i < s1; i += 4) {
                int s = csr_src[i];
                float e = AS[(size_t)s * 2 + myh] + advh;
                e = e > 0.f ? e : NEG_SLOPE * e;
                float pw = __expf(e);
                uint4 hv = *(const uint4*)&H[(size_t)s * 128 + 8 * c];
                const __half2* h2 = (const __half2*)&hv;
#pragma unroll
                for (int j = 0; j < 4; ++j) {
                    float2 f = __half22float2(h2[j]);
                    a[2 * j]     = fmaf(f.x, pw, a[2 * j]);
                    a[2 * j + 1] = fmaf(f.y, pw, a[2 * j + 1]);
                }
            }
        }
#pragma unroll
        for (int j = 0; j < 8; ++j) {
            a[j] += __shfl_xor(a[j], 16, 64);
            a[j] += __shfl_xor(a[j], 32, 64);
        }
        if (lane < 16) {
            float o[8];
            o[0] = a[0] * myinv + bA.x; o[1] = a[1] * myinv + bA.y;
            o[2] = a[2] * myinv + bA.z; o[3] = a[3] * myinv + bA.w;
            o[4] = a[4] * myinv + bB.x; o[5] = a[5] * myinv + bB.y;
            o[6] = a[6] * myinv + bB.z; o[7] = a[7] * myinv + bB.w;
            if (do_relu) {
#pragma unroll
                for (int j = 0; j < 8; ++j) o[j] = fmaxf(o[j], 0.f);
            }
            __half2 hp[4];
#pragma unroll
            for (int j = 0; j < 4; ++j) hp[j] = __floats2half2_rn(o[2 * j], o[2 * j + 1]);
            *(uint4*)&Out[(size_t)n * 128 + 8 * c] = *(uint4*)hp;
        }
    }
}

// ---------- fused GAT per-dst, heads=1, fp16 H, fp32 out (R12 best) ----------
__global__ __launch_bounds__(256) void gat_csr1(const int* __restrict__ offs,
                                                const int* __restrict__ csr_src,
                                                const float* __restrict__ AS,
                                                const float* __restrict__ AD,
                                                const __half* __restrict__ H,
                                                const float* __restrict__ bias,
                                                float* __restrict__ Out,
                                                int N, int do_relu) {
    __shared__ int   sS[4][64];
    __shared__ float sP[4][64];
    const int lane = threadIdx.x & 63;
    const int w = threadIdx.x >> 6;
    const int wid = (int)((blockIdx.x * blockDim.x + threadIdx.x) >> 6);
    const int nw = (int)((gridDim.x * blockDim.x) >> 6);
    const int c = lane & 15;     // channels 4c..4c+3
    const int slot = lane >> 4;  // 4 edge slots
    int* const sSw = &sS[w][0];
    float* const sPw = &sP[w][0];
    const float4 b4 = *(const float4*)&bias[4 * c];

    for (int n = wid; n < N; n += nw) {
        const int s0 = offs[n], s1 = offs[n + 1];
        const int deg = s1 - s0;
        const float adv0 = AD[n];
        float dn0 = 0.f, p0 = 0.f;
        int sreg = 0;
        for (int i = s0 + lane; i < s1; i += 64) {
            int s = csr_src[i];
            float e0 = AS[s] + adv0;
            e0 = e0 > 0.f ? e0 : NEG_SLOPE * e0;
            float pe0 = __expf(e0);
            dn0 += pe0;
            if (i == s0 + lane) { sreg = s; p0 = pe0; }
        }
        for (int o = 1; o < 64; o <<= 1) dn0 += __shfl_xor(dn0, o, 64);
        const float inv0 = 1.f / (dn0 + EPSF);

        float a[4];
#pragma unroll
        for (int j = 0; j < 4; ++j) a[j] = 0.f;
        if (deg <= 64) {
            sSw[lane] = sreg;
            sPw[lane] = p0;
            const int npc = (deg + 3) >> 2;
            int t = 0;
            for (; t + 4 <= npc; t += 4) {
                int ss[4]; float pw[4]; uint2 hv[4];
#pragma unroll
                for (int k = 0; k < 4; ++k) {
                    int idx = 4 * (t + k) + slot;
                    ss[k] = sSw[idx];
                    pw[k] = sPw[idx];
                }
#pragma unroll
                for (int k = 0; k < 4; ++k)
                    hv[k] = *(const uint2*)&H[(size_t)ss[k] * 64 + 4 * c];
#pragma unroll
                for (int k = 0; k < 4; ++k) {
                    const __half2* h2 = (const __half2*)&hv[k];
                    float2 f01 = __half22float2(h2[0]);
                    float2 f23 = __half22float2(h2[1]);
                    a[0] = fmaf(f01.x, pw[k], a[0]);
                    a[1] = fmaf(f01.y, pw[k], a[1]);
                    a[2] = fmaf(f23.x, pw[k], a[2]);
                    a[3] = fmaf(f23.y, pw[k], a[3]);
                }
            }
            for (; t < npc; ++t) {
                int idx = 4 * t + slot;
                int s = sSw[idx];
                float pw = sPw[idx];
                uint2 hv = *(const uint2*)&H[(size_t)s * 64 + 4 * c];
                const __half2* h2 = (const __half2*)&hv;
                float2 f01 = __half22float2(h2[0]);
                float2 f23 = __half22float2(h2[1]);
                a[0] = fmaf(f01.x, pw, a[0]);
                a[1] = fmaf(f01.y, pw, a[1]);
                a[2] = fmaf(f23.x, pw, a[2]);
                a[3] = fmaf(f23.y, pw, a[3]);
            }
        } else {
            for (int i = s0 + slot; i < s1; i += 4) {
                int s = csr_src[i];
                float e = AS[s] + adv0;
                e = e > 0.f ? e : NEG_SLOPE * e;
                float pw = __expf(e);
                uint2 hv = *(const uint2*)&H[(size_t)s * 64 + 4 * c];
                const __half2* h2 = (const __half2*)&hv;
                float2 f01 = __half22float2(h2[0]);
                float2 f23 = __half22float2(h2[1]);
                a[0] = fmaf(f01.x, pw, a[0]);
                a[1] = fmaf(f01.y, pw, a[1]);
                a[2] = fmaf(f23.x, pw, a[2]);
                a[3] = fmaf(f23.y, pw, a[3]);
            }
        }
#pragma unroll
        for (int j = 0; j < 4; ++j) {
            a[j] += __shfl_xor(a[j], 16, 64);
            a[j] += __shfl_xor(a[j], 32, 64);
        }
        if (lane < 16) {
            float4 o;
            o.x = a[0] * inv0 + b4.x;
            o.y = a[1] * inv0 + b4.y;
            o.z = a[2] * inv0 + b4.z;
            o.w = a[3] * inv0 + b4.w;
            if (do_relu) {
                o.x = fmaxf(o.x, 0.f); o.y = fmaxf(o.y, 0.f);
                o.z = fmaxf(o.z, 0.f); o.w = fmaxf(o.w, 0.f);
            }
            *(float4*)&Out[(size_t)n * 64 + 4 * c] = o;
        }
    }
}

extern "C" void kernel_launch(void* const* d_in, const int* in_sizes, int n_in,
                              void* d_out, int out_size, void* d_ws, size_t ws_size,
                              hipStream_t stream) {
    const float* x   = (const float*)d_in[0];
    const int*   ei  = (const int*)d_in[1];
    const float* W0  = (const float*)d_in[2];
    const float* as0 = (const float*)d_in[3];
    const float* ad0 = (const float*)d_in[4];
    const float* b0  = (const float*)d_in[5];
    const float* W1  = (const float*)d_in[6];
    const float* as1 = (const float*)d_in[7];
    const float* ad1 = (const float*)d_in[8];
    const float* b1  = (const float*)d_in[9];
    const float* W2  = (const float*)d_in[10];
    const float* as2 = (const float*)d_in[11];
    const float* ad2 = (const float*)d_in[12];
    const float* b2  = (const float*)d_in[13];

    const int N = in_sizes[0] / 128;
    const int E_raw = in_sizes[1] / 2;
    const int E = E_raw + N;

    char* ws = (char*)d_ws;
    size_t off = 0;
    auto alloc = [&](size_t bytes) {
        void* p = ws + off;
        off = (off + bytes + 255) & ~(size_t)255;
        return p;
    };
    __half* hh    = (__half*)alloc((size_t)N * 128 * 2);  // h (fp16)
    __half* obufh = (__half*)alloc((size_t)N * 128 * 2);  // inter-layer acts fp16
    float* asb  = (float*)alloc((size_t)N * 2 * 4);
    float* adb  = (float*)alloc((size_t)N * 2 * 4);
    int*   cnt  = (int*)alloc((size_t)(N + 4) * 4);
    int*   offs = (int*)alloc((size_t)(N + 1) * 4);
    int*   bsum = (int*)alloc(1024);
    int* csr_src = (int*)alloc((size_t)E * 4);
    (void)ws_size; (void)n_in; (void)out_size;

    // ---- CSR build: single cooperative kernel (zero|hist|scan|scatter) ----
    {
        int* ei_p = (int*)ei;
        void* args[] = { (void*)&ei_p, (void*)&E_raw, (void*)&N,
                         (void*)&cnt, (void*)&offs, (void*)&bsum, (void*)&csr_src };
        hipLaunchCooperativeKernel((void*)csr_build_coop, dim3(1024), dim3(256),
                                   args, 0, stream);
    }

    const int gemm_blocks = (N + 63) / 64;
    const int gat_blocks = 2048;

    // Layer 0: x (fp32, converted in-register) -> obufh (fp16, relu)
    gemm_mfma<128, 2, float><<<gemm_blocks, 256, 0, stream>>>(x, W0, as0, ad0, hh, asb, adb, N);
    gat_csr2<<<gat_blocks, 256, 0, stream>>>(offs, csr_src, asb, adb, hh, b0, obufh, N, 1);
    // Layer 1: obufh (fp16) -> obufh (fp16, relu)
    gemm_mfma<128, 2, __half><<<gemm_blocks, 256, 0, stream>>>(obufh, W1, as1, ad1, hh, asb, adb, N);
    gat_csr2<<<gat_blocks, 256, 0, stream>>>(offs, csr_src, asb, adb, hh, b1, obufh, N, 1);
    // Layer 2: obufh (fp16) -> d_out (fp32, heads=1, no relu); h stored fp16
    gemm_mfma<64, 1, __half><<<gemm_blocks, 256, 0, stream>>>(obufh, W2, as2, ad2, hh, asb, adb, N);
    gat_csr1<<<gat_blocks, 256, 0, stream>>>(offs, csr_src, asb, adb, hh, b2, (float*)d_out, N, 0);
}

// Round 15
// 249.687 us; speedup vs baseline: 2.8513x; 2.8513x over previous
//
#include <hip/hip_runtime.h>
#include <hip/hip_fp16.h>

#define NEG_SLOPE 0.2f
#define EPSF 1e-16f

typedef _Float16 half8 __attribute__((ext_vector_type(8)));
typedef float floatx4 __attribute__((ext_vector_type(4)));

// ---------- MFMA fp16 GEMM + fused alpha epilogue ----------
// C[M,BN] = X[M,128] @ W[128,BN]; X fp16 or fp32 (converted in-register),
// W fp32 -> fp16 in LDS, fp32 MFMA accum. Per wave: 16 rows x BN.
// Layouts (gfx950 16x16x32): A row=lane&15, k=8*(lane>>4)+i; B col=lane&15,
// same k; C/D col=lane&15, row=4*(lane>>4)+reg  [guide-verified].
template<int BN, int HEADS, typename XT>
__global__ __launch_bounds__(256) void gemm_mfma(const XT* __restrict__ X,
                                                 const float* __restrict__ W,
                                                 const float* __restrict__ asrc,
                                                 const float* __restrict__ adst,
                                                 __half* __restrict__ OutH,
                                                 float* __restrict__ AS,
                                                 float* __restrict__ AD, int N) {
    constexpr int KP = 136;           // padded k-stride (f16) for Wt
    constexpr int NF = BN / 16;       // 8 (BN=128) or 4 (BN=64)
    __shared__ _Float16 Wt[BN][KP];
    const int tid = threadIdx.x;
    const int wave = tid >> 6, lane = tid & 63;
    const int r = lane & 15;          // A-row-in-tile / B,C col-in-frag
    const int g = lane >> 4;          // k-group / C row-group
    const int row0 = blockIdx.x * 64 + wave * 16;

    // stage Wt[n][k] = (f16) W[k][n]
    for (int idx = tid; idx < 128 * (BN / 4); idx += 256) {
        int k = idx / (BN / 4), n4 = idx % (BN / 4);
        float4 w4 = *(const float4*)&W[(size_t)k * BN + n4 * 4];
        Wt[n4 * 4 + 0][k] = (_Float16)w4.x;
        Wt[n4 * 4 + 1][k] = (_Float16)w4.y;
        Wt[n4 * 4 + 2][k] = (_Float16)w4.z;
        Wt[n4 * 4 + 3][k] = (_Float16)w4.w;
    }
    __syncthreads();

    const int arow = row0 + r;
    const int arow_c = (arow < N) ? arow : (N - 1);   // clamp; bad rows never stored

    floatx4 acc[NF];
#pragma unroll
    for (int n = 0; n < NF; ++n) acc[n] = (floatx4)(0.f);

#pragma unroll
    for (int ks = 0; ks < 4; ++ks) {   // K-steps of 32
        half8 afrag;
        if constexpr (sizeof(XT) == 2) {
            afrag = *(const half8*)&X[(size_t)arow_c * 128 + ks * 32 + g * 8];
        } else {
            const float* xp = (const float*)&X[(size_t)arow_c * 128 + ks * 32 + g * 8];
            float4 a = *(const float4*)xp;
            float4 b = *(const float4*)(xp + 4);
            afrag[0] = (_Float16)a.x; afrag[1] = (_Float16)a.y;
            afrag[2] = (_Float16)a.z; afrag[3] = (_Float16)a.w;
            afrag[4] = (_Float16)b.x; afrag[5] = (_Float16)b.y;
            afrag[6] = (_Float16)b.z; afrag[7] = (_Float16)b.w;
        }
#pragma unroll
        for (int n = 0; n < NF; ++n) {
            half8 bfrag = *(const half8*)&Wt[n * 16 + r][ks * 32 + g * 8];
            acc[n] = __builtin_amdgcn_mfma_f32_16x16x32_f16(afrag, bfrag, acc[n], 0, 0, 0);
        }
    }

    float av[NF], dv[NF];
#pragma unroll
    for (int n = 0; n < NF; ++n) { av[n] = asrc[n * 16 + r]; dv[n] = adst[n * 16 + r]; }

#pragma unroll
    for (int reg = 0; reg < 4; ++reg) {
        const int orow = row0 + g * 4 + reg;   // uniform across the 16-lane r-group
        if (orow >= N) continue;
#pragma unroll
        for (int n = 0; n < NF; ++n)
            OutH[(size_t)orow * BN + n * 16 + r] = __float2half(acc[n][reg]);
        float ps0 = 0.f, pd0 = 0.f, ps1 = 0.f, pd1 = 0.f;
#pragma unroll
        for (int n = 0; n < NF; ++n) {
            float v = acc[n][reg];
            if (HEADS == 2 && n >= NF / 2) { ps1 = fmaf(v, av[n], ps1); pd1 = fmaf(v, dv[n], pd1); }
            else                           { ps0 = fmaf(v, av[n], ps0); pd0 = fmaf(v, dv[n], pd0); }
        }
#pragma unroll
        for (int o = 1; o < 16; o <<= 1) {
            ps0 += __shfl_xor(ps0, o, 64); pd0 += __shfl_xor(pd0, o, 64);
            if (HEADS == 2) { ps1 += __shfl_xor(ps1, o, 64); pd1 += __shfl_xor(pd1, o, 64); }
        }
        if (r == 0) {
            if (HEADS == 2) {
                AS[orow * 2] = ps0; AS[orow * 2 + 1] = ps1;
                AD[orow * 2] = pd0; AD[orow * 2 + 1] = pd1;
            } else {
                AS[orow] = ps0; AD[orow] = pd0;
            }
        }
    }
}

// ---------- CSR build (separate small kernels: R13 proven-fast path) ----------
__global__ void zero_kernel(int* __restrict__ p, int n4) {
    int i = blockIdx.x * blockDim.x + threadIdx.x;
    if (i < n4) ((int4*)p)[i] = make_int4(0, 0, 0, 0);
}

// XCD-partitioned histogram (cross-XCD atomic line ping-pong fix).
__global__ void hist_part(const int* __restrict__ ei, int E_raw, int N,
                          int* __restrict__ cnt) {
    const int NPART = 8;
    const int part = blockIdx.x & (NPART - 1);
    const int gblocks = gridDim.x >> 3;
    const int grank = blockIdx.x >> 3;
    const int tid = grank * blockDim.x + threadIdx.x;
    const int nthr = gblocks * blockDim.x;
    const int E = E_raw + N;
    const int dlo = (int)(((long long)N * part) / NPART);
    const int dhi = (int)(((long long)N * (part + 1)) / NPART);
    for (int e = tid; e < E; e += nthr) {
        int d = (e < E_raw) ? ei[E_raw + e] : e - E_raw;
        if (d >= dlo && d < dhi) atomicAdd(&cnt[d], 1);
    }
}

__global__ __launch_bounds__(256) void scan_block(const int* __restrict__ cnt,
                                                  int* __restrict__ offs,
                                                  int* __restrict__ bsum, int N) {
    __shared__ int wsum[4];
    const int i = blockIdx.x * 256 + threadIdx.x;
    const int lane = threadIdx.x & 63, w = threadIdx.x >> 6;
    int v = (i < N) ? cnt[i] : 0;
    int incl = v;
    for (int o = 1; o < 64; o <<= 1) {
        int t = __shfl_up(incl, o, 64);
        if (lane >= o) incl += t;
    }
    if (lane == 63) wsum[w] = incl;
    __syncthreads();
    int prefix = 0;
    for (int k = 0; k < w; ++k) prefix += wsum[k];
    if (i < N) offs[i] = prefix + incl - v;
    if (threadIdx.x == 255) bsum[blockIdx.x] = prefix + incl;
}

__global__ __launch_bounds__(256) void scan_bsum(int* __restrict__ bsum, int nb) {
    __shared__ int wsum[4];
    const int lane = threadIdx.x & 63, w = threadIdx.x >> 6;
    int v = (threadIdx.x < nb) ? bsum[threadIdx.x] : 0;
    int incl = v;
    for (int o = 1; o < 64; o <<= 1) {
        int t = __shfl_up(incl, o, 64);
        if (lane >= o) incl += t;
    }
    if (lane == 63) wsum[w] = incl;
    __syncthreads();
    int prefix = 0;
    for (int k = 0; k < w; ++k) prefix += wsum[k];
    if (threadIdx.x < nb) bsum[threadIdx.x] = prefix + incl - v;
}

__global__ void scan_add(int* __restrict__ offs, const int* __restrict__ bsum,
                         int N, int E) {
    const int i = blockIdx.x * 256 + threadIdx.x;
    if (i < N) offs[i] += bsum[blockIdx.x];
    if (i == 0) offs[N] = E;
}

// XCD-partitioned scatter (R5). pos = offs[d] + (--cnt[d]); cnt ends at 0.
__global__ void scatter_edges_part(const int* __restrict__ ei, int E_raw, int N,
                                   int* __restrict__ cnt,
                                   const int* __restrict__ offs,
                                   int* __restrict__ csr_src) {
    const int NPART = 8;
    const int part = blockIdx.x & (NPART - 1);
    const int gblocks = gridDim.x >> 3;
    const int grank = blockIdx.x >> 3;
    const int tid = grank * blockDim.x + threadIdx.x;
    const int nthr = gblocks * blockDim.x;
    const int E = E_raw + N;
    const int dlo = (int)(((long long)N * part) / NPART);
    const int dhi = (int)(((long long)N * (part + 1)) / NPART);
    for (int e = tid; e < E; e += nthr) {
        int d = (e < E_raw) ? ei[E_raw + e] : e - E_raw;
        if (d >= dlo && d < dhi) {
            int s = (e < E_raw) ? ei[e] : d;
            int old = atomicSub(&cnt[d], 1);
            csr_src[offs[d] + old - 1] = s;
        }
    }
}

// ---------- fused GAT per-dst, heads=2, fp16 H, fp16 out (R12 best) ----------
__global__ __launch_bounds__(256) void gat_csr2(const int* __restrict__ offs,
                                                const int* __restrict__ csr_src,
                                                const float* __restrict__ AS,
                                                const float* __restrict__ AD,
                                                const __half* __restrict__ H,
                                                const float* __restrict__ bias,
                                                __half* __restrict__ Out,
                                                int N, int do_relu) {
    __shared__ int   sS[4][64];
    __shared__ float sP0[4][64];
    __shared__ float sP1[4][64];
    const int lane = threadIdx.x & 63;
    const int w = threadIdx.x >> 6;
    const int wid = (int)((blockIdx.x * blockDim.x + threadIdx.x) >> 6);
    const int nw = (int)((gridDim.x * blockDim.x) >> 6);
    const int c = lane & 15;      // channels 8c..8c+7
    const int slot = lane >> 4;   // 4 edge slots
    const int myh = c >> 3;       // head owning my channels
    int* const sSw = &sS[w][0];
    const float* const myp = myh ? &sP1[w][0] : &sP0[w][0];
    const float4 bA = *(const float4*)&bias[8 * c];
    const float4 bB = *(const float4*)&bias[8 * c + 4];

    for (int n = wid; n < N; n += nw) {
        const int s0 = offs[n], s1 = offs[n + 1];
        const int deg = s1 - s0;
        const float2 adv = *(const float2*)&AD[(size_t)n * 2];
        float dn0 = 0.f, dn1 = 0.f, p0 = 0.f, p1 = 0.f;
        int sreg = 0;
        for (int i = s0 + lane; i < s1; i += 64) {
            int s = csr_src[i];
            float2 a2 = *(const float2*)&AS[(size_t)s * 2];
            float e0 = a2.x + adv.x, e1 = a2.y + adv.y;
            e0 = e0 > 0.f ? e0 : NEG_SLOPE * e0;
            e1 = e1 > 0.f ? e1 : NEG_SLOPE * e1;
            float pe0 = __expf(e0), pe1 = __expf(e1);
            dn0 += pe0; dn1 += pe1;
            if (i == s0 + lane) { sreg = s; p0 = pe0; p1 = pe1; }
        }
        for (int o = 1; o < 64; o <<= 1) {
            dn0 += __shfl_xor(dn0, o, 64);
            dn1 += __shfl_xor(dn1, o, 64);
        }
        const float myinv = 1.f / ((myh ? dn1 : dn0) + EPSF);

        float a[8];
#pragma unroll
        for (int j = 0; j < 8; ++j) a[j] = 0.f;
        if (deg <= 64) {
            sSw[lane] = sreg;       // phantom lanes: s=0, p=0
            sP0[w][lane] = p0;
            sP1[w][lane] = p1;
            const int npc = (deg + 3) >> 2;   // quads; phantom edges have p=0
            int t = 0;
            for (; t + 4 <= npc; t += 4) {
                int ss[4]; float pw[4]; uint4 hv[4];
#pragma unroll
                for (int k = 0; k < 4; ++k) {
                    int idx = 4 * (t + k) + slot;
                    ss[k] = sSw[idx];
                    pw[k] = myp[idx];
                }
#pragma unroll
                for (int k = 0; k < 4; ++k)
                    hv[k] = *(const uint4*)&H[(size_t)ss[k] * 128 + 8 * c];
#pragma unroll
                for (int k = 0; k < 4; ++k) {
                    const __half2* h2 = (const __half2*)&hv[k];
#pragma unroll
                    for (int j = 0; j < 4; ++j) {
                        float2 f = __half22float2(h2[j]);
                        a[2 * j]     = fmaf(f.x, pw[k], a[2 * j]);
                        a[2 * j + 1] = fmaf(f.y, pw[k], a[2 * j + 1]);
                    }
                }
            }
            for (; t < npc; ++t) {
                int idx = 4 * t + slot;
                int s = sSw[idx];
                float pw = myp[idx];
                uint4 hv = *(const uint4*)&H[(size_t)s * 128 + 8 * c];
                const __half2* h2 = (const __half2*)&hv;
#pragma unroll
                for (int j = 0; j < 4; ++j) {
                    float2 f = __half22float2(h2[j]);
                    a[2 * j]     = fmaf(f.x, pw, a[2 * j]);
                    a[2 * j + 1] = fmaf(f.y, pw, a[2 * j + 1]);
                }
            }
        } else {
            const float advh = myh ? adv.y : adv.x;
            for (int i = s0 + slot; i < s1; i += 4) {
                int s = csr_src[i];
                float e = AS[(size_t)s * 2 + myh] + advh;
                e = e > 0.f ? e : NEG_SLOPE * e;
                float pw = __expf(e);
                uint4 hv = *(const uint4*)&H[(size_t)s * 128 + 8 * c];
                const __half2* h2 = (const __half2*)&hv;
#pragma unroll
                for (int j = 0; j < 4; ++j) {
                    float2 f = __half22float2(h2[j]);
                    a[2 * j]     = fmaf(f.x, pw, a[2 * j]);
                    a[2 * j + 1] = fmaf(f.y, pw, a[2 * j + 1]);
                }
            }
        }
#pragma unroll
        for (int j = 0; j < 8; ++j) {
            a[j] += __shfl_xor(a[j], 16, 64);
            a[j] += __shfl_xor(a[j], 32, 64);
        }
        if (lane < 16) {
            float o[8];
            o[0] = a[0] * myinv + bA.x; o[1] = a[1] * myinv + bA.y;
            o[2] = a[2] * myinv + bA.z; o[3] = a[3] * myinv + bA.w;
            o[4] = a[4] * myinv + bB.x; o[5] = a[5] * myinv + bB.y;
            o[6] = a[6] * myinv + bB.z; o[7] = a[7] * myinv + bB.w;
            if (do_relu) {
#pragma unroll
                for (int j = 0; j < 8; ++j) o[j] = fmaxf(o[j], 0.f);
            }
            __half2 hp[4];
#pragma unroll
            for (int j = 0; j < 4; ++j) hp[j] = __floats2half2_rn(o[2 * j], o[2 * j + 1]);
            *(uint4*)&Out[(size_t)n * 128 + 8 * c] = *(uint4*)hp;
        }
    }
}

// ---------- fused GAT per-dst, heads=1, fp16 H, fp32 out (R12 best) ----------
__global__ __launch_bounds__(256) void gat_csr1(const int* __restrict__ offs,
                                                const int* __restrict__ csr_src,
                                                const float* __restrict__ AS,
                                                const float* __restrict__ AD,
                                                const __half* __restrict__ H,
                                                const float* __restrict__ bias,
                                                float* __restrict__ Out,
                                                int N, int do_relu) {
    __shared__ int   sS[4][64];
    __shared__ float sP[4][64];
    const int lane = threadIdx.x & 63;
    const int w = threadIdx.x >> 6;
    const int wid = (int)((blockIdx.x * blockDim.x + threadIdx.x) >> 6);
    const int nw = (int)((gridDim.x * blockDim.x) >> 6);
    const int c = lane & 15;     // channels 4c..4c+3
    const int slot = lane >> 4;  // 4 edge slots
    int* const sSw = &sS[w][0];
    float* const sPw = &sP[w][0];
    const float4 b4 = *(const float4*)&bias[4 * c];

    for (int n = wid; n < N; n += nw) {
        const int s0 = offs[n], s1 = offs[n + 1];
        const int deg = s1 - s0;
        const float adv0 = AD[n];
        float dn0 = 0.f, p0 = 0.f;
        int sreg = 0;
        for (int i = s0 + lane; i < s1; i += 64) {
            int s = csr_src[i];
            float e0 = AS[s] + adv0;
            e0 = e0 > 0.f ? e0 : NEG_SLOPE * e0;
            float pe0 = __expf(e0);
            dn0 += pe0;
            if (i == s0 + lane) { sreg = s; p0 = pe0; }
        }
        for (int o = 1; o < 64; o <<= 1) dn0 += __shfl_xor(dn0, o, 64);
        const float inv0 = 1.f / (dn0 + EPSF);

        float a[4];
#pragma unroll
        for (int j = 0; j < 4; ++j) a[j] = 0.f;
        if (deg <= 64) {
            sSw[lane] = sreg;
            sPw[lane] = p0;
            const int npc = (deg + 3) >> 2;
            int t = 0;
            for (; t + 4 <= npc; t += 4) {
                int ss[4]; float pw[4]; uint2 hv[4];
#pragma unroll
                for (int k = 0; k < 4; ++k) {
                    int idx = 4 * (t + k) + slot;
                    ss[k] = sSw[idx];
                    pw[k] = sPw[idx];
                }
#pragma unroll
                for (int k = 0; k < 4; ++k)
                    hv[k] = *(const uint2*)&H[(size_t)ss[k] * 64 + 4 * c];
#pragma unroll
                for (int k = 0; k < 4; ++k) {
                    const __half2* h2 = (const __half2*)&hv[k];
                    float2 f01 = __half22float2(h2[0]);
                    float2 f23 = __half22float2(h2[1]);
                    a[0] = fmaf(f01.x, pw[k], a[0]);
                    a[1] = fmaf(f01.y, pw[k], a[1]);
                    a[2] = fmaf(f23.x, pw[k], a[2]);
                    a[3] = fmaf(f23.y, pw[k], a[3]);
                }
            }
            for (; t < npc; ++t) {
                int idx = 4 * t + slot;
                int s = sSw[idx];
                float pw = sPw[idx];
                uint2 hv = *(const uint2*)&H[(size_t)s * 64 + 4 * c];
                const __half2* h2 = (const __half2*)&hv;
                float2 f01 = __half22float2(h2[0]);
                float2 f23 = __half22float2(h2[1]);
                a[0] = fmaf(f01.x, pw, a[0]);
                a[1] = fmaf(f01.y, pw, a[1]);
                a[2] = fmaf(f23.x, pw, a[2]);
                a[3] = fmaf(f23.y, pw, a[3]);
            }
        } else {
            for (int i = s0 + slot; i < s1; i += 4) {
                int s = csr_src[i];
                float e = AS[s] + adv0;
                e = e > 0.f ? e : NEG_SLOPE * e;
                float pw = __expf(e);
                uint2 hv = *(const uint2*)&H[(size_t)s * 64 + 4 * c];
                const __half2* h2 = (const __half2*)&hv;
                float2 f01 = __half22float2(h2[0]);
                float2 f23 = __half22float2(h2[1]);
                a[0] = fmaf(f01.x, pw, a[0]);
                a[1] = fmaf(f01.y, pw, a[1]);
                a[2] = fmaf(f23.x, pw, a[2]);
                a[3] = fmaf(f23.y, pw, a[3]);
            }
        }
#pragma unroll
        for (int j = 0; j < 4; ++j) {
            a[j] += __shfl_xor(a[j], 16, 64);
            a[j] += __shfl_xor(a[j], 32, 64);
        }
        if (lane < 16) {
            float4 o;
            o.x = a[0] * inv0 + b4.x;
            o.y = a[1] * inv0 + b4.y;
            o.z = a[2] * inv0 + b4.z;
            o.w = a[3] * inv0 + b4.w;
            if (do_relu) {
                o.x = fmaxf(o.x, 0.f); o.y = fmaxf(o.y, 0.f);
                o.z = fmaxf(o.z, 0.f); o.w = fmaxf(o.w, 0.f);
            }
            *(float4*)&Out[(size_t)n * 64 + 4 * c] = o;
        }
    }
}

extern "C" void kernel_launch(void* const* d_in, const int* in_sizes, int n_in,
                              void* d_out, int out_size, void* d_ws, size_t ws_size,
                              hipStream_t stream) {
    const float* x   = (const float*)d_in[0];
    const int*   ei  = (const int*)d_in[1];
    const float* W0  = (const float*)d_in[2];
    const float* as0 = (const float*)d_in[3];
    const float* ad0 = (const float*)d_in[4];
    const float* b0  = (const float*)d_in[5];
    const float* W1  = (const float*)d_in[6];
    const float* as1 = (const float*)d_in[7];
    const float* ad1 = (const float*)d_in[8];
    const float* b1  = (const float*)d_in[9];
    const float* W2  = (const float*)d_in[10];
    const float* as2 = (const float*)d_in[11];
    const float* ad2 = (const float*)d_in[12];
    const float* b2  = (const float*)d_in[13];

    const int N = in_sizes[0] / 128;
    const int E_raw = in_sizes[1] / 2;
    const int E = E_raw + N;

    char* ws = (char*)d_ws;
    size_t off = 0;
    auto alloc = [&](size_t bytes) {
        void* p = ws + off;
        off = (off + bytes + 255) & ~(size_t)255;
        return p;
    };
    __half* hh    = (__half*)alloc((size_t)N * 128 * 2);  // h (fp16)
    __half* obufh = (__half*)alloc((size_t)N * 128 * 2);  // inter-layer acts fp16
    float* asb  = (float*)alloc((size_t)N * 2 * 4);
    float* adb  = (float*)alloc((size_t)N * 2 * 4);
    int*   cnt  = (int*)alloc((size_t)(N + 4) * 4);
    int*   offs = (int*)alloc((size_t)(N + 1) * 4);
    int*   bsum = (int*)alloc(1024);
    int* csr_src = (int*)alloc((size_t)E * 4);
    (void)ws_size; (void)n_in; (void)out_size;

    // ---- build CSR grouped by dst (reused by all 3 layers) ----
    const int nb = (N + 255) / 256;
    const int n4 = (N + 3) / 4;
    zero_kernel<<<(n4 + 255) / 256, 256, 0, stream>>>(cnt, n4);
    hist_part<<<2048, 256, 0, stream>>>(ei, E_raw, N, cnt);
    scan_block<<<nb, 256, 0, stream>>>(cnt, offs, bsum, N);
    scan_bsum<<<1, 256, 0, stream>>>(bsum, nb);
    scan_add<<<nb, 256, 0, stream>>>(offs, bsum, N, E);
    scatter_edges_part<<<2048, 256, 0, stream>>>(ei, E_raw, N, cnt, offs, csr_src);

    const int gemm_blocks = (N + 63) / 64;
    const int gat_blocks = 2048;

    // Layer 0: x (fp32, converted in-register) -> obufh (fp16, relu)
    gemm_mfma<128, 2, float><<<gemm_blocks, 256, 0, stream>>>(x, W0, as0, ad0, hh, asb, adb, N);
    gat_csr2<<<gat_blocks, 256, 0, stream>>>(offs, csr_src, asb, adb, hh, b0, obufh, N, 1);
    // Layer 1: obufh (fp16) -> obufh (fp16, relu)
    gemm_mfma<128, 2, __half><<<gemm_blocks, 256, 0, stream>>>(obufh, W1, as1, ad1, hh, asb, adb, N);
    gat_csr2<<<gat_blocks, 256, 0, stream>>>(offs, csr_src, asb, adb, hh, b1, obufh, N, 1);
    // Layer 2: obufh (fp16) -> d_out (fp32, heads=1, no relu); h stored fp16
    gemm_mfma<64, 1, __half><<<gemm_blocks, 256, 0, stream>>>(obufh, W2, as2, ad2, hh, asb, adb, N);
    gat_csr1<<<gat_blocks, 256, 0, stream>>>(offs, csr_src, asb, adb, hh, b2, (float*)d_out, N, 0);
}